// Round 4
// baseline (180.387 us; speedup 1.0000x reference)
//
#include <hip/hip_runtime.h>

#define NG 20000
#define NB 1024

typedef float v4f __attribute__((ext_vector_type(4)));

constexpr int THREADS = 256;            // 4 waves
constexpr int GENES_PER_BLOCK = 512;    // 128 gene-lanes * 4 genes
constexpr int NGB = 40;                 // ceil(20000/512)
constexpr int BB  = 16;                 // batches per block
constexpr int NBB = NB / BB;            // 64
constexpr int BB_PER_XCD = NBB / 8;     // 8 batch-chunks per XCD

// R2 structure (half-wave tech split, 64 VGPR) + max occupancy:
// grid 2560 = 8 resident blocks/CU = 32 waves/CU for latency hiding.
// lanes 0-31 = tech0, lanes 32-63 = tech1, same genes; 4 genes/thread;
// params in registers; NT float4 load of x, NT half-wave store of out.
__global__ __launch_bounds__(THREADS, 8)
void cgm_kernel(const float* __restrict__ x,
                const float* __restrict__ w1,
                const float* __restrict__ b1,
                const float* __restrict__ w2,
                const float* __restrict__ b2,
                const float* __restrict__ wg,
                const float* __restrict__ bg,
                float* __restrict__ out)
{
    // XCD mapping: each XCD owns all 40 gene-chunks x 8 batch-chunks.
    // Param set (2.4MB) fits one XCD L2; x stripe (21MB) streams through.
    const int bid = (int)blockIdx.x;          // 0..2559
    const int xcd = bid & 7;
    const int j   = bid >> 3;                 // 0..319
    const int gb  = j % NGB;                  // 0..39
    const int bb  = xcd * BB_PER_XCD + j / NGB;

    const int lane = (int)threadIdx.x & 63;
    const int wv   = (int)threadIdx.x >> 6;
    const int t    = lane >> 5;               // tech 0/1 per half-wave
    const int gl   = wv * 32 + (lane & 31);   // gene-lane 0..127
    const int gbase = gb * GENES_PER_BLOCK + gl * 4;
    if (gbase >= NG) return;                  // tail (gb==39): partners stay paired

    // ---- per-thread params in registers (own tech only) ----
    v4f W1[4], B1[4], W2[4];
    float B2v[4];
    const size_t r0 = (size_t)t * NG + (size_t)gbase;
    #pragma unroll
    for (int g = 0; g < 4; ++g) {
        W1[g]  = *(const v4f*)(w1 + (r0 + g) * 4);
        B1[g]  = *(const v4f*)(b1 + (r0 + g) * 4);
        W2[g]  = *(const v4f*)(w2 + (r0 + g) * 4);
        B2v[g] = b2[r0 + g];
    }
    const v4f wgA = *(const v4f*)(wg + (size_t)gbase * 2);      // g0t0 g0t1 g1t0 g1t1
    const v4f wgB = *(const v4f*)(wg + (size_t)gbase * 2 + 4);  // g2t0 g2t1 g3t0 g3t1
    const v4f bgv = *(const v4f*)(bg + gbase);

    const float* xbase = x + (size_t)t * NG + (size_t)gbase;
    float*       obase = out + (size_t)gbase;

    const int b_lo = bb * BB;
    #pragma unroll 4
    for (int bi = 0; bi < BB; ++bi) {
        const size_t b = (size_t)(b_lo + bi);
        const v4f xv = __builtin_nontemporal_load((const v4f*)(xbase + b * (2 * NG)));

        float s[4];
        #pragma unroll
        for (int g = 0; g < 4; ++g) {
            const float v = xv[g];
            float h, acc = 0.f;
            h = fmaxf(fmaf(v, W1[g].x, B1[g].x), 0.f); acc = fmaf(h, W2[g].x, acc);
            h = fmaxf(fmaf(v, W1[g].y, B1[g].y), 0.f); acc = fmaf(h, W2[g].y, acc);
            h = fmaxf(fmaf(v, W1[g].z, B1[g].z), 0.f); acc = fmaf(h, W2[g].z, acc);
            h = fmaxf(fmaf(v, W1[g].w, B1[g].w), 0.f); acc = fmaf(h, W2[g].w, acc);
            s[g] = fmaxf(acc + B2v[g], 0.f);
        }

        // exchange shrink outputs across the tech half-waves (partner = lane^32)
        float so[4];
        #pragma unroll
        for (int g = 0; g < 4; ++g) so[g] = __shfl_xor(s[g], 32, 64);

        if (t == 0) {   // lanes 0-31 hold (s=tech0, so=tech1): combine + store
            v4f o;
            o.x = fmaxf(fmaf(s[0], wgA.x, fmaf(so[0], wgA.y, bgv.x)), 0.f);
            o.y = fmaxf(fmaf(s[1], wgA.z, fmaf(so[1], wgA.w, bgv.y)), 0.f);
            o.z = fmaxf(fmaf(s[2], wgB.x, fmaf(so[2], wgB.y, bgv.z)), 0.f);
            o.w = fmaxf(fmaf(s[3], wgB.z, fmaf(so[3], wgB.w, bgv.w)), 0.f);
            __builtin_nontemporal_store(o, (v4f*)(obase + b * NG));
        }
    }
}

extern "C" void kernel_launch(void* const* d_in, const int* in_sizes, int n_in,
                              void* d_out, int out_size, void* d_ws, size_t ws_size,
                              hipStream_t stream) {
    const float* x  = (const float*)d_in[0];
    const float* w1 = (const float*)d_in[1];
    const float* b1 = (const float*)d_in[2];
    const float* w2 = (const float*)d_in[3];
    const float* b2 = (const float*)d_in[4];
    const float* wg = (const float*)d_in[5];
    const float* bg = (const float*)d_in[6];
    float* out = (float*)d_out;

    dim3 grid(NGB * NBB);   // 40 * 64 = 2560 blocks (8 resident per CU)
    cgm_kernel<<<grid, THREADS, 0, stream>>>(x, w1, b1, w2, b2, wg, bg, out);
}

// Round 5
// 58.158 us; speedup vs baseline: 3.1017x; 3.1017x over previous
//
#include <hip/hip_runtime.h>

#define NG 20000
#define NB 1024

typedef float v4f __attribute__((ext_vector_type(4)));

constexpr int THREADS = 256;            // 4 waves
constexpr int GENES_PER_BLOCK = 512;    // 128 gene-lanes * 4 genes
constexpr int NGB = 40;                 // ceil(20000/512)
constexpr int BB  = 16;                 // batches per block
constexpr int NBB = NB / BB;            // 64
constexpr int GB_PER_XCD = NGB / 8;     // 5 gene-chunks per XCD

// R2 structure (half-wave tech split): lanes 0-31 = tech0, lanes 32-63 =
// tech1, same genes; 4 genes/thread; params in registers (~64 VGPR).
// launch_bounds(256,4): do NOT squeeze VGPR below the param set (R4 lesson:
// (256,8) -> 32 VGPR -> params re-loaded per batch iter -> 3.3x regression).
// Grid 2560 = 8 blocks/CU = 32 waves/CU for latency hiding (R2 was 20).
__global__ __launch_bounds__(THREADS, 4)
void cgm_kernel(const float* __restrict__ x,
                const float* __restrict__ w1,
                const float* __restrict__ b1,
                const float* __restrict__ w2,
                const float* __restrict__ b2,
                const float* __restrict__ wg,
                const float* __restrict__ bg,
                float* __restrict__ out)
{
    // XCD mapping (R2's, proven): each XCD owns 5 gene-chunks x 64
    // batch-chunks -> param working set ~300KB in its L2.
    const int bid = (int)blockIdx.x;          // 0..2559
    const int xcd = bid & 7;
    const int j   = bid >> 3;                 // 0..319
    const int gb  = xcd * GB_PER_XCD + (j / NBB);   // 0..39
    const int bb  = j % NBB;                  // 0..63

    const int lane = (int)threadIdx.x & 63;
    const int wv   = (int)threadIdx.x >> 6;
    const int t    = lane >> 5;               // tech 0/1 per half-wave
    const int gl   = wv * 32 + (lane & 31);   // gene-lane 0..127
    const int gbase = gb * GENES_PER_BLOCK + gl * 4;
    if (gbase >= NG) return;                  // tail (gb==39): partners stay paired

    // ---- per-thread params in registers (own tech only) ----
    v4f W1[4], B1[4], W2[4];
    float B2v[4];
    const size_t r0 = (size_t)t * NG + (size_t)gbase;
    #pragma unroll
    for (int g = 0; g < 4; ++g) {
        W1[g]  = *(const v4f*)(w1 + (r0 + g) * 4);
        B1[g]  = *(const v4f*)(b1 + (r0 + g) * 4);
        W2[g]  = *(const v4f*)(w2 + (r0 + g) * 4);
        B2v[g] = b2[r0 + g];
    }
    const v4f wgA = *(const v4f*)(wg + (size_t)gbase * 2);      // g0t0 g0t1 g1t0 g1t1
    const v4f wgB = *(const v4f*)(wg + (size_t)gbase * 2 + 4);  // g2t0 g2t1 g3t0 g3t1
    const v4f bgv = *(const v4f*)(bg + gbase);

    const float* xbase = x + (size_t)t * NG + (size_t)gbase;
    float*       obase = out + (size_t)gbase;

    const int b_lo = bb * BB;
    #pragma unroll 4
    for (int bi = 0; bi < BB; ++bi) {
        const size_t b = (size_t)(b_lo + bi);
        const v4f xv = __builtin_nontemporal_load((const v4f*)(xbase + b * (2 * NG)));

        float s[4];
        #pragma unroll
        for (int g = 0; g < 4; ++g) {
            const float v = xv[g];
            float h, acc = 0.f;
            h = fmaxf(fmaf(v, W1[g].x, B1[g].x), 0.f); acc = fmaf(h, W2[g].x, acc);
            h = fmaxf(fmaf(v, W1[g].y, B1[g].y), 0.f); acc = fmaf(h, W2[g].y, acc);
            h = fmaxf(fmaf(v, W1[g].z, B1[g].z), 0.f); acc = fmaf(h, W2[g].z, acc);
            h = fmaxf(fmaf(v, W1[g].w, B1[g].w), 0.f); acc = fmaf(h, W2[g].w, acc);
            s[g] = fmaxf(acc + B2v[g], 0.f);
        }

        // exchange shrink outputs across the tech half-waves (partner = lane^32)
        float so[4];
        #pragma unroll
        for (int g = 0; g < 4; ++g) so[g] = __shfl_xor(s[g], 32, 64);

        if (t == 0) {   // lanes 0-31 hold (s=tech0, so=tech1): combine + store
            v4f o;
            o.x = fmaxf(fmaf(s[0], wgA.x, fmaf(so[0], wgA.y, bgv.x)), 0.f);
            o.y = fmaxf(fmaf(s[1], wgA.z, fmaf(so[1], wgA.w, bgv.y)), 0.f);
            o.z = fmaxf(fmaf(s[2], wgB.x, fmaf(so[2], wgB.y, bgv.z)), 0.f);
            o.w = fmaxf(fmaf(s[3], wgB.z, fmaf(so[3], wgB.w, bgv.w)), 0.f);
            __builtin_nontemporal_store(o, (v4f*)(obase + b * NG));
        }
    }
}

extern "C" void kernel_launch(void* const* d_in, const int* in_sizes, int n_in,
                              void* d_out, int out_size, void* d_ws, size_t ws_size,
                              hipStream_t stream) {
    const float* x  = (const float*)d_in[0];
    const float* w1 = (const float*)d_in[1];
    const float* b1 = (const float*)d_in[2];
    const float* w2 = (const float*)d_in[3];
    const float* b2 = (const float*)d_in[4];
    const float* wg = (const float*)d_in[5];
    const float* bg = (const float*)d_in[6];
    float* out = (float*)d_out;

    dim3 grid(NGB * NBB);   // 40 * 64 = 2560 blocks (8 resident per CU)
    cgm_kernel<<<grid, THREADS, 0, stream>>>(x, w1, b1, w2, b2, wg, bg, out);
}

// Round 6
// 52.995 us; speedup vs baseline: 3.4039x; 1.0974x over previous
//
#include <hip/hip_runtime.h>

#define NG 20000
#define NB 1024

typedef float v4f __attribute__((ext_vector_type(4)));

constexpr int THREADS = 256;            // 4 waves
constexpr int GENES_PER_BLOCK = 512;    // 128 gene-lanes * 4 genes
constexpr int NGB = 40;                 // ceil(20000/512)
constexpr int BB  = 32;                 // batches per block
constexpr int NBB = NB / BB;            // 32
constexpr int GB_PER_XCD = NGB / 8;     // 5 gene-chunks per XCD

// R2 structure (half-wave tech split, params in registers) + 8-deep
// software pipeline on the x stream: two rotating groups of 4 NT loads
// keep 4-8KB outstanding per wave (R2 had 1KB -> latency-limited 4.5TB/s).
// launch_bounds(256,4): R4 lesson — never squeeze VGPR below the param set.
__global__ __launch_bounds__(THREADS, 4)
void cgm_kernel(const float* __restrict__ x,
                const float* __restrict__ w1,
                const float* __restrict__ b1,
                const float* __restrict__ w2,
                const float* __restrict__ b2,
                const float* __restrict__ wg,
                const float* __restrict__ bg,
                float* __restrict__ out)
{
    // XCD mapping (R2's): each XCD owns 5 gene-chunks x 32 batch-chunks.
    const int bid = (int)blockIdx.x;          // 0..1279
    const int xcd = bid & 7;
    const int j   = bid >> 3;                 // 0..159
    const int gb  = xcd * GB_PER_XCD + (j / NBB);   // 0..39
    const int bb  = j % NBB;                  // 0..31

    const int lane = (int)threadIdx.x & 63;
    const int wv   = (int)threadIdx.x >> 6;
    const int t    = lane >> 5;               // tech 0/1 per half-wave
    const int gl   = wv * 32 + (lane & 31);   // gene-lane 0..127
    const int gbase = gb * GENES_PER_BLOCK + gl * 4;
    if (gbase >= NG) return;                  // tail (gb==39): partners stay paired

    // ---- per-thread params in registers (own tech only) ----
    v4f W1[4], B1[4], W2[4];
    float B2v[4];
    const size_t r0 = (size_t)t * NG + (size_t)gbase;
    #pragma unroll
    for (int g = 0; g < 4; ++g) {
        W1[g]  = *(const v4f*)(w1 + (r0 + g) * 4);
        B1[g]  = *(const v4f*)(b1 + (r0 + g) * 4);
        W2[g]  = *(const v4f*)(w2 + (r0 + g) * 4);
        B2v[g] = b2[r0 + g];
    }
    const v4f wgA = *(const v4f*)(wg + (size_t)gbase * 2);      // g0t0 g0t1 g1t0 g1t1
    const v4f wgB = *(const v4f*)(wg + (size_t)gbase * 2 + 4);  // g2t0 g2t1 g3t0 g3t1
    const v4f bgv = *(const v4f*)(bg + gbase);

    const float* xbase = x + (size_t)t * NG + (size_t)gbase;
    float*       obase = out + (size_t)gbase;
    const int b_lo = bb * BB;

    auto load4 = [&](v4f* dst, int bi) {
        #pragma unroll
        for (int k = 0; k < 4; ++k)
            dst[k] = __builtin_nontemporal_load(
                (const v4f*)(xbase + (size_t)(b_lo + bi + k) * (2 * NG)));
    };
    auto proc1 = [&](v4f xv, int b_abs) {
        float s[4];
        #pragma unroll
        for (int g = 0; g < 4; ++g) {
            const float v = xv[g];
            float h, acc = 0.f;
            h = fmaxf(fmaf(v, W1[g].x, B1[g].x), 0.f); acc = fmaf(h, W2[g].x, acc);
            h = fmaxf(fmaf(v, W1[g].y, B1[g].y), 0.f); acc = fmaf(h, W2[g].y, acc);
            h = fmaxf(fmaf(v, W1[g].z, B1[g].z), 0.f); acc = fmaf(h, W2[g].z, acc);
            h = fmaxf(fmaf(v, W1[g].w, B1[g].w), 0.f); acc = fmaf(h, W2[g].w, acc);
            s[g] = fmaxf(acc + B2v[g], 0.f);
        }
        float so[4];
        #pragma unroll
        for (int g = 0; g < 4; ++g) so[g] = __shfl_xor(s[g], 32, 64);
        if (t == 0) {
            v4f o;
            o.x = fmaxf(fmaf(s[0], wgA.x, fmaf(so[0], wgA.y, bgv.x)), 0.f);
            o.y = fmaxf(fmaf(s[1], wgA.z, fmaf(so[1], wgA.w, bgv.y)), 0.f);
            o.z = fmaxf(fmaf(s[2], wgB.x, fmaf(so[2], wgB.y, bgv.z)), 0.f);
            o.w = fmaxf(fmaf(s[3], wgB.z, fmaf(so[3], wgB.w, bgv.w)), 0.f);
            __builtin_nontemporal_store(o, (v4f*)(obase + (size_t)b_abs * NG));
        }
    };

    v4f A[4], B[4];
    load4(A, 0);
    load4(B, 4);
    #pragma unroll
    for (int bi = 0; bi < BB; bi += 8) {
        #pragma unroll
        for (int k = 0; k < 4; ++k) proc1(A[k], b_lo + bi + k);
        if (bi + 8 < BB) load4(A, bi + 8);
        #pragma unroll
        for (int k = 0; k < 4; ++k) proc1(B[k], b_lo + bi + 4 + k);
        if (bi + 12 < BB) load4(B, bi + 12);
    }
}

extern "C" void kernel_launch(void* const* d_in, const int* in_sizes, int n_in,
                              void* d_out, int out_size, void* d_ws, size_t ws_size,
                              hipStream_t stream) {
    const float* x  = (const float*)d_in[0];
    const float* w1 = (const float*)d_in[1];
    const float* b1 = (const float*)d_in[2];
    const float* w2 = (const float*)d_in[3];
    const float* b2 = (const float*)d_in[4];
    const float* wg = (const float*)d_in[5];
    const float* bg = (const float*)d_in[6];
    float* out = (float*)d_out;

    dim3 grid(NGB * NBB);   // 40 * 32 = 1280 blocks
    cgm_kernel<<<grid, THREADS, 0, stream>>>(x, w1, b1, w2, b2, wg, bg, out);
}